// Round 19
// baseline (4425.880 us; speedup 1.0000x reference)
//
#include <hip/hip_runtime.h>
#include <hip/hip_bf16.h>

#define T_STEPS 512
#define BATCH   256
#define HID     100
#define GATES   400   // 4*H
#define BT      (BATCH * T_STEPS)
#define NB      16    // batches per recur block

__device__ __forceinline__ float sigm_f(float x) {
    return 1.f / (1.f + __expf(-x));
}

__device__ __forceinline__ float tanh_f(float x) {
    float ax = fabsf(x);
    float t  = __expf(-2.f * ax);
    float r  = (1.f - t) / (1.f + t);
    return copysignf(r, x);
}

// fp32 -> bf16 (RNE) and back, as raw ushort bits
__device__ __forceinline__ unsigned short bf_hi(float f) {
    unsigned u = __float_as_uint(f);
    return (unsigned short)((u + 0x7FFFu + ((u >> 16) & 1u)) >> 16);
}
__device__ __forceinline__ float bf_f(unsigned short s) {
    return __uint_as_float(((unsigned)s) << 16);
}

typedef short v8s __attribute__((ext_vector_type(8)));   // 8 bf16 bit-patterns
typedef float v4f __attribute__((ext_vector_type(4)));

__device__ __forceinline__ void split8(float4 a, float4 b, v8s& hi, v8s& lo) {
    float f[8] = {a.x, a.y, a.z, a.w, b.x, b.y, b.z, b.w};
    short h[8], l[8];
#pragma unroll
    for (int e = 0; e < 8; ++e) {
        unsigned short hh = bf_hi(f[e]);
        h[e] = (short)hh;
        l[e] = (short)bf_hi(f[e] - bf_f(hh));
    }
    hi = (v8s){h[0], h[1], h[2], h[3], h[4], h[5], h[6], h[7]};
    lo = (v8s){l[0], l[1], l[2], l[3], l[4], l[5], l[6], l[7]};
}

// ---------------------------------------------------------------------------
// xg GEMM v8 (MFMA bf16x3), unchanged since round 12 (absmax 0.0).
// ---------------------------------------------------------------------------
template <int K, int NK, bool GATHER>
__global__ __launch_bounds__(256) void xg_gemm(
    const float* __restrict__ A, const int* __restrict__ idx,
    const float* __restrict__ W, const float* __restrict__ b1,
    const float* __restrict__ b2, float* __restrict__ out)
{
    __shared__ unsigned short Ah[2][4096], Al[2][4096];
    __shared__ unsigned short Wh[2][4096], Wl[2][4096];
    __shared__ int idx_s[128];

    const int bid  = blockIdx.x;
    const int xcd  = bid & 7;
    const int rest = bid >> 3;
    const int ct   = rest & 3;
    const int rgrp = rest >> 2;
    const int row0 = (rgrp * 8 + xcd) * 128;
    const int col0 = ct * 128;

    const int tid  = threadIdx.x;
    const int lane = tid & 63;
    const int wave = tid >> 6;
    const int wm   = wave >> 1;
    const int wn   = wave & 1;
    const int lm   = lane & 15;
    const int lk   = lane >> 4;

    if (GATHER) {
        if (tid < 128) idx_s[tid] = idx[row0 + tid];
        __syncthreads();
    }

    const int sr = tid >> 1;
    const int sq = (tid & 1) * 4;
    const float* arowp = GATHER ? (A + (size_t)idx_s[sr] * K)
                                : (A + (size_t)(row0 + sr) * K);
    const int    wrow  = col0 + sr;
    const bool   wval  = (wrow < GATES);
    const float* wrowp = W + (size_t)wrow * K;

    auto stage = [&](int ks, int buf) {
        const int k0 = ks * 32;
#pragma unroll
        for (int u = 0; u < 4; ++u) {
            int q  = sq + u;
            int kb = k0 + q * 4;
            float4 va = make_float4(0.f, 0.f, 0.f, 0.f);
            float4 vw = make_float4(0.f, 0.f, 0.f, 0.f);
            if (kb < K) {
                va = *(const float4*)(arowp + kb);
                if (wval) vw = *(const float4*)(wrowp + kb);
            }
            int bo = sr * 64 + q * 8;
            int so = bo ^ (((bo >> 6) & 7) << 4);
            v8s hi, lo;
            split8(va, make_float4(0,0,0,0), hi, lo);  // only first 4 used
            // pack 4 bf16 hi/lo manually (8-wide helper writes 4 valid)
            unsigned short h0 = bf_hi(va.x), h1 = bf_hi(va.y),
                           h2 = bf_hi(va.z), h3 = bf_hi(va.w);
            *(ushort4*)((char*)Ah[buf] + so) = make_ushort4(h0, h1, h2, h3);
            *(ushort4*)((char*)Al[buf] + so) = make_ushort4(
                bf_hi(va.x - bf_f(h0)), bf_hi(va.y - bf_f(h1)),
                bf_hi(va.z - bf_f(h2)), bf_hi(va.w - bf_f(h3)));
            h0 = bf_hi(vw.x); h1 = bf_hi(vw.y);
            h2 = bf_hi(vw.z); h3 = bf_hi(vw.w);
            *(ushort4*)((char*)Wh[buf] + so) = make_ushort4(h0, h1, h2, h3);
            *(ushort4*)((char*)Wl[buf] + so) = make_ushort4(
                bf_hi(vw.x - bf_f(h0)), bf_hi(vw.y - bf_f(h1)),
                bf_hi(vw.z - bf_f(h2)), bf_hi(vw.w - bf_f(h3)));
        }
    };

    stage(0, 0);

    v4f acc[4][4];
#pragma unroll
    for (int fm = 0; fm < 4; ++fm)
#pragma unroll
        for (int fn = 0; fn < 4; ++fn)
            acc[fm][fn] = (v4f){0.f, 0.f, 0.f, 0.f};

#pragma unroll 1
    for (int ks = 0; ks < NK; ++ks) {
        __syncthreads();
        if (ks + 1 < NK) stage(ks + 1, (ks + 1) & 1);

        const int cur = ks & 1;
        v8s ah[4], al[4], bh[4], bl[4];
#pragma unroll
        for (int f = 0; f < 4; ++f) {
            int ra = (wm * 64 + f * 16 + lm) * 64 + lk * 16;
            ra ^= ((ra >> 6) & 7) << 4;
            ah[f] = *(const v8s*)((const char*)Ah[cur] + ra);
            al[f] = *(const v8s*)((const char*)Al[cur] + ra);
            int rb = (wn * 64 + f * 16 + lm) * 64 + lk * 16;
            rb ^= ((rb >> 6) & 7) << 4;
            bh[f] = *(const v8s*)((const char*)Wh[cur] + rb);
            bl[f] = *(const v8s*)((const char*)Wl[cur] + rb);
        }
#pragma unroll
        for (int fm = 0; fm < 4; ++fm) {
#pragma unroll
            for (int fn = 0; fn < 4; ++fn) {
                acc[fm][fn] = __builtin_amdgcn_mfma_f32_16x16x32_bf16(
                    ah[fm], bh[fn], acc[fm][fn], 0, 0, 0);
                acc[fm][fn] = __builtin_amdgcn_mfma_f32_16x16x32_bf16(
                    ah[fm], bl[fn], acc[fm][fn], 0, 0, 0);
                acc[fm][fn] = __builtin_amdgcn_mfma_f32_16x16x32_bf16(
                    al[fm], bh[fn], acc[fm][fn], 0, 0, 0);
            }
        }
    }

#pragma unroll
    for (int fn = 0; fn < 4; ++fn) {
        int col = col0 + wn * 64 + fn * 16 + lm;
        if (col < GATES) {
            float bias = b1[col] + b2[col];
#pragma unroll
            for (int fm = 0; fm < 4; ++fm) {
                v4f d = acc[fm][fn];
                int rbase = row0 + wm * 64 + fm * 16 + lk * 4;
#pragma unroll
                for (int p = 0; p < 4; ++p)
                    out[(size_t)(rbase + p) * GATES + col] = d[p] + bias;
            }
        }
    }
}

// ---------------------------------------------------------------------------
// Recurrent scan vMFMA: 16 batches/block, 16 blocks, 512 threads (8 waves).
// Per step: G[16,400] = H[16,100] @ W_hh^T via mfma_f32_16x16x32_bf16, bf16x3
// split for fp32 accuracy. W frags loaded ONCE via pool (LDS) which h_hist
// later overwrites -> remat impossible; AGPR residency is FREE for MFMA B.
// H kept in LDS as bf16 hi/lo (XOR-swizzled rows). xg prefetched 2 steps
// deep in registers. Gates routed via g_buf LDS; c/h update 4 units/thread.
// ---------------------------------------------------------------------------
template <bool WRITE_ALL>
__global__ __launch_bounds__(512, 2) void lstm_recur_mfma(
    const float* __restrict__ xg,    // [B, T, 400]
    const float* __restrict__ w_hh,  // [400, 100]
    const int*   __restrict__ lengths,
    float* __restrict__ hs)          // [B, T, 100]
{
    const int tid  = threadIdx.x;
    const int lane = tid & 63;
    const int w    = tid >> 6;       // wave 0..7
    const int lm   = lane & 15;
    const int lk   = lane >> 4;      // 0..3
    const int b0   = blockIdx.x * NB;

    __shared__ float pool[14336];            // W-stage [112][128] -> h_hist [8][16][100]
    __shared__ float g_buf[NB][404];         // padded: lk-groups hit distinct banks
    __shared__ unsigned short H_hi[NB * 128], H_lo[NB * 128];
    __shared__ int len_s[NB];

    // per-slot constants: tile ct = w + 8*i covers cols [ct*16, ct*16+16)
    int  colI[4]; bool act[4], ist[4];
#pragma unroll
    for (int i = 0; i < 4; ++i) {
        int ct = w + 8 * i;
        act[i]  = (ct < 25);
        colI[i] = ct * 16 + lm;
        ist[i]  = act[i] && (colI[i] >= 200 && colI[i] < 300);
    }

    // ---- W fragment staging via pool (4 chunks of 112 cols x 128 k) ----
    v8s wh[4][4], wl[4][4];
    const v8s vz = (v8s){0,0,0,0,0,0,0,0};
#pragma unroll
    for (int i = 0; i < 4; ++i)
#pragma unroll
        for (int ks = 0; ks < 4; ++ks) { wh[i][ks] = vz; wl[i][ks] = vz; }

    for (int c = 0; c < 4; ++c) {
        for (int e = tid; e < 3584; e += 512) {        // [112][32 float4]
            int colL = e >> 5, k4 = e & 31;
            int col = c * 112 + colL, k = k4 * 4;
            float4 v = make_float4(0.f, 0.f, 0.f, 0.f);
            if (col < GATES && k < HID)
                v = *(const float4*)(w_hh + (size_t)col * HID + k);
            int byteo = (e << 4) ^ ((colL & 7) << 4);
            *(float4*)((char*)pool + byteo) = v;
        }
        __syncthreads();
#pragma unroll
        for (int i = 0; i < 4; ++i) {
            int ct = w + 8 * i;
            if (act[i] && (ct / 7) == c) {
                int colL = colI[i] - c * 112;
#pragma unroll
                for (int ks = 0; ks < 4; ++ks) {
                    int base = colL * 128 + ks * 32 + lk * 8;
                    int o1 = (base << 2) ^ ((colL & 7) << 4);
                    int o2 = ((base + 4) << 2) ^ ((colL & 7) << 4);
                    float4 u0 = *(const float4*)((const char*)pool + o1);
                    float4 u1 = *(const float4*)((const char*)pool + o2);
                    split8(u0, u1, wh[i][ks], wl[i][ks]);
                }
            }
        }
        __syncthreads();
    }

    // ---- init state ----
    for (int i2 = tid; i2 < NB * 128; i2 += 512) { H_hi[i2] = 0; H_lo[i2] = 0; }
    if (tid < NB) len_s[tid] = lengths[b0 + tid];

    int ub[4], uj[4]; bool uact[4];
    float cc[4] = {0.f, 0.f, 0.f, 0.f}, hv[4] = {0.f, 0.f, 0.f, 0.f};
#pragma unroll
    for (int r = 0; r < 4; ++r) {
        int u = tid + 512 * r;
        uact[r] = (u < NB * HID);
        int uu = uact[r] ? u : 0;
        ub[r] = uu / HID; uj[r] = uu % HID;
    }
    __syncthreads();
    int ulen[4];
#pragma unroll
    for (int r = 0; r < 4; ++r) ulen[r] = len_s[ub[r]];

    // xg row bases per p (batch = b0 + lk*4 + p)
    size_t rowb[4];
#pragma unroll
    for (int p = 0; p < 4; ++p)
        rowb[p] = ((size_t)(b0 + lk * 4 + p) * T_STEPS) * GATES;

    // 2-deep xg prefetch
    float xpA[4][4], xpB[4][4];
#pragma unroll
    for (int i = 0; i < 4; ++i) if (act[i]) {
#pragma unroll
        for (int p = 0; p < 4; ++p) {
            xpA[i][p] = xg[rowb[p] + colI[i]];          // t=0
            xpB[i][p] = xg[rowb[p] + GATES + colI[i]];  // t=1
        }
    }

    for (int t = 0; t < T_STEPS; ++t) {
        // Phase A+B: A-frags streamed per kstep; MFMA into acc
        v4f acc[4];
#pragma unroll
        for (int i = 0; i < 4; ++i) acc[i] = (v4f){0.f, 0.f, 0.f, 0.f};
#pragma unroll
        for (int ks = 0; ks < 4; ++ks) {
            int ob = ((lm * 128 + ks * 32 + lk * 8) << 1) ^ ((lm & 7) << 4);
            v8s ah = *(const v8s*)((const char*)H_hi + ob);
            v8s al = *(const v8s*)((const char*)H_lo + ob);
#pragma unroll
            for (int i = 0; i < 4; ++i) if (act[i]) {
                acc[i] = __builtin_amdgcn_mfma_f32_16x16x32_bf16(ah, wh[i][ks], acc[i], 0, 0, 0);
                acc[i] = __builtin_amdgcn_mfma_f32_16x16x32_bf16(ah, wl[i][ks], acc[i], 0, 0, 0);
                acc[i] = __builtin_amdgcn_mfma_f32_16x16x32_bf16(al, wh[i][ks], acc[i], 0, 0, 0);
            }
        }

        // Phase C: pre-act + activation -> g_buf; refill xg prefetch for t+2
        auto cphase = [&](float (&XP)[4][4]) {
#pragma unroll
            for (int i = 0; i < 4; ++i) if (act[i]) {
#pragma unroll
                for (int p = 0; p < 4; ++p) {
                    float pre = acc[i][p] + XP[i][p];
                    float xx  = ist[i] ? pre + pre : pre;
                    float s   = 1.f / (1.f + __expf(-xx));
                    float a   = ist[i] ? s + s - 1.f : s;
                    g_buf[lk * 4 + p][colI[i]] = a;
                }
                if (t + 2 < T_STEPS) {
#pragma unroll
                    for (int p = 0; p < 4; ++p)
                        XP[i][p] = xg[rowb[p] + (size_t)(t + 2) * GATES + colI[i]];
                }
            }
        };
        if ((t & 1) == 0) cphase(xpA); else cphase(xpB);
        __syncthreads();

        // Phase D: c/h update (4 units/thread), write H bf16 + h_hist
#pragma unroll
        for (int r = 0; r < 4; ++r) if (uact[r]) {
            float gi = g_buf[ub[r]][uj[r]];
            float gf = g_buf[ub[r]][HID + uj[r]];
            float gg = g_buf[ub[r]][2 * HID + uj[r]];
            float go = g_buf[ub[r]][3 * HID + uj[r]];
            float cn = gf * cc[r] + gi * gg;
            float hn = go * tanh_f(cn);
            bool  m  = (t < ulen[r]);
            cc[r] = m ? cn : cc[r];
            hv[r] = m ? hn : hv[r];
            unsigned short hb = bf_hi(hv[r]);
            unsigned short lb = bf_hi(hv[r] - bf_f(hb));
            int ob = ((ub[r] * 128 + uj[r]) << 1) ^ ((ub[r] & 7) << 4);
            *(unsigned short*)((char*)H_hi + ob) = hb;
            *(unsigned short*)((char*)H_lo + ob) = lb;
            // always write pool (kills W remat for both template variants)
            pool[(t & 7) * (NB * HID) + tid + 512 * r] = hv[r];
        }
        __syncthreads();

        if (WRITE_ALL && (t & 7) == 7) {
            int tb = t - 7;
            for (int e2 = tid; e2 < 3200; e2 += 512) {
                float4 v = ((const float4*)pool)[e2];
                int ts  = e2 / 400;
                int rem = e2 % 400;
                int bb = rem / 25, j4 = rem % 25;
                *(float4*)(hs + ((size_t)(b0 + bb) * T_STEPS + (tb + ts)) * HID + j4 * 4) = v;
            }
        }
    }

    if (!WRITE_ALL) {
#pragma unroll
        for (int r = 0; r < 4; ++r) if (uact[r])
            hs[((size_t)(b0 + ub[r]) * T_STEPS + (T_STEPS - 1)) * HID + uj[r]] = hv[r];
    }
}

// ---------------------------------------------------------------------------
// Final linear head
// ---------------------------------------------------------------------------
__global__ __launch_bounds__(64) void fc_kernel(
    const float* __restrict__ hs, const float* __restrict__ w_fc,
    const float* __restrict__ b_fc, float* __restrict__ out)
{
    int tid = blockIdx.x * 64 + threadIdx.x;
    if (tid >= BATCH * 3) return;
    int b = tid / 3, o = tid % 3;
    const float* h = hs + ((size_t)b * T_STEPS + (T_STEPS - 1)) * HID;
    float acc = b_fc[o];
    for (int j = 0; j < HID; ++j) acc += h[j] * w_fc[o * HID + j];
    out[b * 3 + o] = acc;
}

extern "C" void kernel_launch(void* const* d_in, const int* in_sizes, int n_in,
                              void* d_out, int out_size, void* d_ws, size_t ws_size,
                              hipStream_t stream)
{
    const int*   x       = (const int*)  d_in[0];
    const int*   lengths = (const int*)  d_in[1];
    const float* emb     = (const float*)d_in[2];
    const float* w_ih0   = (const float*)d_in[3];
    const float* w_hh0   = (const float*)d_in[4];
    const float* b_ih0   = (const float*)d_in[5];
    const float* b_hh0   = (const float*)d_in[6];
    const float* w_ih1   = (const float*)d_in[7];
    const float* w_hh1   = (const float*)d_in[8];
    const float* b_ih1   = (const float*)d_in[9];
    const float* b_hh1   = (const float*)d_in[10];
    const float* w_ih2   = (const float*)d_in[11];
    const float* w_hh2   = (const float*)d_in[12];
    const float* b_ih2   = (const float*)d_in[13];
    const float* b_hh2   = (const float*)d_in[14];
    const float* w_fc    = (const float*)d_in[15];
    const float* b_fc    = (const float*)d_in[16];
    float* out = (float*)d_out;

    float* xg = (float*)d_ws;                  // [BT, 400]  ~210 MB
    float* hs = xg + (size_t)BT * GATES;       // [BT, 100]  ~52 MB

    const int nblk = (BT / 128) * 4;   // 4096, XCD-swizzled inside kernel

    // Layer 0: embedding gather fused into staging, K=300 (pad 320)
    xg_gemm<300, 10, true><<<nblk, 256, 0, stream>>>(emb, x, w_ih0, b_ih0, b_hh0, xg);
    lstm_recur_mfma<true><<<BATCH / NB, 512, 0, stream>>>(xg, w_hh0, lengths, hs);

    // Layer 1: K=100 (pad 128)
    xg_gemm<100, 4, false><<<nblk, 256, 0, stream>>>(hs, nullptr, w_ih1, b_ih1, b_hh1, xg);
    lstm_recur_mfma<true><<<BATCH / NB, 512, 0, stream>>>(xg, w_hh1, lengths, hs);

    // Layer 2
    xg_gemm<100, 4, false><<<nblk, 256, 0, stream>>>(hs, nullptr, w_ih2, b_ih2, b_hh2, xg);
    lstm_recur_mfma<false><<<BATCH / NB, 512, 0, stream>>>(xg, w_hh2, lengths, hs);

    // Head
    fc_kernel<<<(BATCH * 3 + 63) / 64, 64, 0, stream>>>(hs, w_fc, b_fc, out);
}

// Round 21
// 1872.592 us; speedup vs baseline: 2.3635x; 2.3635x over previous
//
#include <hip/hip_runtime.h>
#include <hip/hip_bf16.h>

#define T_STEPS 512
#define BATCH   256
#define HID     100
#define GATES   400   // 4*H
#define BT      (BATCH * T_STEPS)

__device__ __forceinline__ float sigm_f(float x) {
    return 1.f / (1.f + __expf(-x));
}

__device__ __forceinline__ float tanh_f(float x) {
    float ax = fabsf(x);
    float t  = __expf(-2.f * ax);
    float r  = (1.f - t) / (1.f + t);
    return copysignf(r, x);
}

// fp32 -> bf16 (RNE) and back, as raw ushort bits
__device__ __forceinline__ unsigned short bf_hi(float f) {
    unsigned u = __float_as_uint(f);
    return (unsigned short)((u + 0x7FFFu + ((u >> 16) & 1u)) >> 16);
}
__device__ __forceinline__ float bf_f(unsigned short s) {
    return __uint_as_float(((unsigned)s) << 16);
}

typedef short v8s __attribute__((ext_vector_type(8)));   // 8 bf16 bit-patterns
typedef float v4f __attribute__((ext_vector_type(4)));

// ---------------------------------------------------------------------------
// xg GEMM v9 (MFMA bf16x3 + LENGTH EARLY-EXIT):
// rows past len[batch] are consumed only by masked (discarded) LSTM steps,
// so tiles whose whole 128-step t-range is >= len[batch] exit immediately.
// Mean len ~ 256/512 -> ~half the tiles exit -> ~half the GEMM time+writes.
// Core unchanged since round 12 (absmax 0.0): D += Ah*Bh + Ah*Bl + Al*Bh,
// BM=128, BN=128, K-step 32, dbuf LDS, XOR swizzle, XCD swizzle.
// ---------------------------------------------------------------------------
template <int K, int NK, bool GATHER>
__global__ __launch_bounds__(256) void xg_gemm(
    const float* __restrict__ A, const int* __restrict__ idx,
    const float* __restrict__ W, const float* __restrict__ b1,
    const float* __restrict__ b2, const int* __restrict__ lengths,
    float* __restrict__ out)
{
    __shared__ unsigned short Ah[2][4096], Al[2][4096];   // 128 rows x 32 k
    __shared__ unsigned short Wh[2][4096], Wl[2][4096];
    __shared__ int idx_s[128];

    const int bid  = blockIdx.x;
    const int xcd  = bid & 7;
    const int rest = bid >> 3;
    const int ct   = rest & 3;
    const int rgrp = rest >> 2;
    const int row0 = (rgrp * 8 + xcd) * 128;
    const int col0 = ct * 128;

    // length early-exit: this tile covers t in [row0&511, +128) of one batch
    if ((row0 & 511) >= lengths[row0 >> 9]) return;

    const int tid  = threadIdx.x;
    const int lane = tid & 63;
    const int wave = tid >> 6;
    const int wm   = wave >> 1;
    const int wn   = wave & 1;
    const int lm   = lane & 15;
    const int lk   = lane >> 4;

    if (GATHER) {
        if (tid < 128) idx_s[tid] = idx[row0 + tid];
        __syncthreads();
    }

    const int sr = tid >> 1;
    const int sq = (tid & 1) * 4;
    const float* arowp = GATHER ? (A + (size_t)idx_s[sr] * K)
                                : (A + (size_t)(row0 + sr) * K);
    const int    wrow  = col0 + sr;
    const bool   wval  = (wrow < GATES);
    const float* wrowp = W + (size_t)wrow * K;

    auto stage = [&](int ks, int buf) {
        const int k0 = ks * 32;
#pragma unroll
        for (int u = 0; u < 4; ++u) {
            int q  = sq + u;
            int kb = k0 + q * 4;
            float4 va = make_float4(0.f, 0.f, 0.f, 0.f);
            float4 vw = make_float4(0.f, 0.f, 0.f, 0.f);
            if (kb < K) {
                va = *(const float4*)(arowp + kb);
                if (wval) vw = *(const float4*)(wrowp + kb);
            }
            int bo = sr * 64 + q * 8;
            int so = bo ^ (((bo >> 6) & 7) << 4);
            unsigned short h0 = bf_hi(va.x), h1 = bf_hi(va.y),
                           h2 = bf_hi(va.z), h3 = bf_hi(va.w);
            *(ushort4*)((char*)Ah[buf] + so) = make_ushort4(h0, h1, h2, h3);
            *(ushort4*)((char*)Al[buf] + so) = make_ushort4(
                bf_hi(va.x - bf_f(h0)), bf_hi(va.y - bf_f(h1)),
                bf_hi(va.z - bf_f(h2)), bf_hi(va.w - bf_f(h3)));
            h0 = bf_hi(vw.x); h1 = bf_hi(vw.y);
            h2 = bf_hi(vw.z); h3 = bf_hi(vw.w);
            *(ushort4*)((char*)Wh[buf] + so) = make_ushort4(h0, h1, h2, h3);
            *(ushort4*)((char*)Wl[buf] + so) = make_ushort4(
                bf_hi(vw.x - bf_f(h0)), bf_hi(vw.y - bf_f(h1)),
                bf_hi(vw.z - bf_f(h2)), bf_hi(vw.w - bf_f(h3)));
        }
    };

    stage(0, 0);

    v4f acc[4][4];
#pragma unroll
    for (int fm = 0; fm < 4; ++fm)
#pragma unroll
        for (int fn = 0; fn < 4; ++fn)
            acc[fm][fn] = (v4f){0.f, 0.f, 0.f, 0.f};

#pragma unroll 1
    for (int ks = 0; ks < NK; ++ks) {
        __syncthreads();
        if (ks + 1 < NK) stage(ks + 1, (ks + 1) & 1);

        const int cur = ks & 1;
        v8s ah[4], al[4], bh[4], bl[4];
#pragma unroll
        for (int f = 0; f < 4; ++f) {
            int ra = (wm * 64 + f * 16 + lm) * 64 + lk * 16;
            ra ^= ((ra >> 6) & 7) << 4;
            ah[f] = *(const v8s*)((const char*)Ah[cur] + ra);
            al[f] = *(const v8s*)((const char*)Al[cur] + ra);
            int rb = (wn * 64 + f * 16 + lm) * 64 + lk * 16;
            rb ^= ((rb >> 6) & 7) << 4;
            bh[f] = *(const v8s*)((const char*)Wh[cur] + rb);
            bl[f] = *(const v8s*)((const char*)Wl[cur] + rb);
        }
#pragma unroll
        for (int fm = 0; fm < 4; ++fm) {
#pragma unroll
            for (int fn = 0; fn < 4; ++fn) {
                acc[fm][fn] = __builtin_amdgcn_mfma_f32_16x16x32_bf16(
                    ah[fm], bh[fn], acc[fm][fn], 0, 0, 0);
                acc[fm][fn] = __builtin_amdgcn_mfma_f32_16x16x32_bf16(
                    ah[fm], bl[fn], acc[fm][fn], 0, 0, 0);
                acc[fm][fn] = __builtin_amdgcn_mfma_f32_16x16x32_bf16(
                    al[fm], bh[fn], acc[fm][fn], 0, 0, 0);
            }
        }
    }

#pragma unroll
    for (int fn = 0; fn < 4; ++fn) {
        int col = col0 + wn * 64 + fn * 16 + lm;
        if (col < GATES) {
            float bias = b1[col] + b2[col];
#pragma unroll
            for (int fm = 0; fm < 4; ++fm) {
                v4f d = acc[fm][fn];
                int rbase = row0 + wm * 64 + fm * 16 + lk * 4;
#pragma unroll
                for (int p = 0; p < 4; ++p)
                    out[(size_t)(rbase + p) * GATES + col] = d[p] + bias;
            }
        }
    }
}

// pack 25 floats into 7 named v4f (pads zero)
#define LOADW(W0, W1, W2, W3, W4, W5, W6, P)                 \
    W0 = (v4f){(P)[0],  (P)[1],  (P)[2],  (P)[3]};           \
    W1 = (v4f){(P)[4],  (P)[5],  (P)[6],  (P)[7]};           \
    W2 = (v4f){(P)[8],  (P)[9],  (P)[10], (P)[11]};          \
    W3 = (v4f){(P)[12], (P)[13], (P)[14], (P)[15]};          \
    W4 = (v4f){(P)[16], (P)[17], (P)[18], (P)[19]};          \
    W5 = (v4f){(P)[20], (P)[21], (P)[22], (P)[23]};          \
    W6 = (v4f){(P)[24], 0.f, 0.f, 0.f};

#define DOT4(S, W, H)                                        \
    S += (W).x * (H).x; S += (W).y * (H).y;                  \
    S += (W).z * (H).z; S += (W).w * (H).w;

// ---------------------------------------------------------------------------
// Recurrent scan v11 = round-16 best (490 us) + LENGTH EARLY-EXIT:
// run only ceil32(len[b]) steps; hs[t>=len] == h[len-1] (mask holds state),
// so the tail is a block-fill of h_final. Early-exiting blocks also halve
// the AGGREGATE L2 weight-refetch traffic (the co-binding resource), so
// long-batch blocks speed up as the grid drains.
// Weight registers are v4f (ext_vector_type) -- round-20 compile fix: the
// (v4f){...} literals in LOADW don't convert to HIP float4.
// ---------------------------------------------------------------------------
template <bool WRITE_ALL>
__global__ __launch_bounds__(448) void lstm_recur(
    const float* __restrict__ xg,    // [B, T, 400]
    const float* __restrict__ w_hh,  // [400, 100]
    const int*   __restrict__ lengths,
    float* __restrict__ hs)          // [B, T, 100]
{
    const int b   = blockIdx.x;
    const int tid = threadIdx.x;
    const bool active = (tid < 400);
    const int j   = tid >> 2;
    const int jc  = (j < HID) ? j : (HID - 1);
    const int gt  = tid & 3;

    __shared__ float xg_s[32 * GATES];
    __shared__ float h_s[2][112];
    __shared__ float h_hist[32 * HID];

    v4f w00, w01, w02, w03, w04, w05, w06;   // gate 0 (i)
    v4f w10, w11, w12, w13, w14, w15, w16;   // gate 1 (f)
    v4f w20, w21, w22, w23, w24, w25, w26;   // gate 2 (g)
    v4f w30, w31, w32, w33, w34, w35, w36;   // gate 3 (o)
    {
        const float* p0 = w_hh + (size_t)(0 * HID + jc) * HID + gt * 25;
        const float* p1 = w_hh + (size_t)(1 * HID + jc) * HID + gt * 25;
        const float* p2 = w_hh + (size_t)(2 * HID + jc) * HID + gt * 25;
        const float* p3 = w_hh + (size_t)(3 * HID + jc) * HID + gt * 25;
        LOADW(w00, w01, w02, w03, w04, w05, w06, p0)
        LOADW(w10, w11, w12, w13, w14, w15, w16, p1)
        LOADW(w20, w21, w22, w23, w24, w25, w26, p2)
        LOADW(w30, w31, w32, w33, w34, w35, w36, p3)
    }

    for (int i = tid; i < 224; i += 448) ((float*)h_s)[i] = 0.f;

    float c_reg = 0.f, h_reg = 0.f;
    const int len   = lengths[b];
    const int t_end = (len + 31) & ~31;   // chunk-aligned; len>=1 -> >=32, <=512
    const float* xgb = xg + (size_t)b * T_STEPS * GATES;
    float*       hsb = hs + (size_t)b * T_STEPS * HID;

    const bool is0 = (gt == 0), is1 = (gt == 1), is2 = (gt == 2);
    const int  hoff = gt * 28;
    const int  seg  = (jc / 25) * 28 + (jc % 25);
    const int  xcol = gt * HID + jc;

    for (int t = 0; t < t_end; ++t) {
        if ((t & 31) == 0) {
            if (WRITE_ALL && t > 0) {
                const float4* s = (const float4*)h_hist;
                float4*       d = (float4*)(hsb + (size_t)(t - 32) * HID);
                for (int i = tid; i < 800; i += 448) d[i] = s[i];
            }
            const float4* src = (const float4*)(xgb + (size_t)t * GATES);
            float4*       dst = (float4*)xg_s;
            for (int i = tid; i < 3200; i += 448) dst[i] = src[i];
            __syncthreads();
        }

        float s0 = 0.f, s1 = 0.f, s2 = 0.f, s3 = 0.f;
        {
            const v4f* hb = (const v4f*)(h_s[t & 1] + hoff);
            v4f ha = hb[0], hb1 = hb[1], hc = hb[2], hd = hb[3],
                he = hb[4], hf = hb[5], hg = hb[6];
            DOT4(s0, w00, ha) DOT4(s0, w01, hb1) DOT4(s0, w02, hc)
            DOT4(s0, w03, hd) DOT4(s0, w04, he)  DOT4(s0, w05, hf)
            DOT4(s0, w06, hg)
            DOT4(s1, w10, ha) DOT4(s1, w11, hb1) DOT4(s1, w12, hc)
            DOT4(s1, w13, hd) DOT4(s1, w14, he)  DOT4(s1, w15, hf)
            DOT4(s1, w16, hg)
            DOT4(s2, w20, ha) DOT4(s2, w21, hb1) DOT4(s2, w22, hc)
            DOT4(s2, w23, hd) DOT4(s2, w24, he)  DOT4(s2, w25, hf)
            DOT4(s2, w26, hg)
            DOT4(s3, w30, ha) DOT4(s3, w31, hb1) DOT4(s3, w32, hc)
            DOT4(s3, w33, hd) DOT4(s3, w34, he)  DOT4(s3, w35, hf)
            DOT4(s3, w36, hg)
        }
        s0 += __shfl_xor(s0, 1); s0 += __shfl_xor(s0, 2);
        s1 += __shfl_xor(s1, 1); s1 += __shfl_xor(s1, 2);
        s2 += __shfl_xor(s2, 1); s2 += __shfl_xor(s2, 2);
        s3 += __shfl_xor(s3, 1); s3 += __shfl_xor(s3, 2);

        float sg  = is0 ? s0 : is1 ? s1 : is2 ? s2 : s3;
        float pre = sg + xg_s[(t & 31) * GATES + xcol];

        float p0 = is2 ? tanh_f(pre) : sigm_f(pre);
        float p1 = __shfl_xor(p0, 1);
        float p2 = __shfl_xor(p0, 2);
        float p3 = __shfl_xor(p1, 2);
        float iv = is0 ? p0 : is1 ? p1 : is2 ? p2 : p3;
        float fv = is0 ? p1 : is1 ? p0 : is2 ? p3 : p2;
        float gv = is0 ? p2 : is1 ? p3 : is2 ? p0 : p1;
        float ov = is0 ? p3 : is1 ? p2 : is2 ? p1 : p0;

        float c_new = fv * c_reg + iv * gv;
        float h_new = ov * tanh_f(c_new);
        bool  m     = (t < len);
        c_reg = m ? c_new : c_reg;
        h_reg = m ? h_new : h_reg;

        if (active && gt == 0) {
            h_s[(t & 1) ^ 1][seg] = h_reg;
            if (WRITE_ALL) h_hist[(t & 31) * HID + j] = h_reg;
        }
        __syncthreads();
    }

    if (WRITE_ALL) {
        // flush last executed chunk [t_end-32, t_end)
        {
            const float4* s = (const float4*)h_hist;
            float4*       d = (float4*)(hsb + (size_t)(t_end - 32) * HID);
            for (int i = tid; i < 800; i += 448) d[i] = s[i];
        }
        // fill [t_end, T) with h_final (mask held state; hs[t>=len]=h[len-1])
        const float* hfin = h_s[t_end & 1];
        for (int e = tid; e < (T_STEPS - t_end) * HID; e += 448) {
            int t = t_end + e / HID, jj = e % HID;
            hsb[(size_t)t * HID + jj] = hfin[(jj / 25) * 28 + (jj % 25)];
        }
    } else {
        // last layer: fc reads only hs[b, T-1, :] = h_final
        if (active && gt == 0)
            hsb[(size_t)(T_STEPS - 1) * HID + j] = h_reg;
    }
}

// ---------------------------------------------------------------------------
// Final linear head
// ---------------------------------------------------------------------------
__global__ __launch_bounds__(64) void fc_kernel(
    const float* __restrict__ hs, const float* __restrict__ w_fc,
    const float* __restrict__ b_fc, float* __restrict__ out)
{
    int tid = blockIdx.x * 64 + threadIdx.x;
    if (tid >= BATCH * 3) return;
    int b = tid / 3, o = tid % 3;
    const float* h = hs + ((size_t)b * T_STEPS + (T_STEPS - 1)) * HID;
    float acc = b_fc[o];
    for (int j = 0; j < HID; ++j) acc += h[j] * w_fc[o * HID + j];
    out[b * 3 + o] = acc;
}

extern "C" void kernel_launch(void* const* d_in, const int* in_sizes, int n_in,
                              void* d_out, int out_size, void* d_ws, size_t ws_size,
                              hipStream_t stream)
{
    const int*   x       = (const int*)  d_in[0];
    const int*   lengths = (const int*)  d_in[1];
    const float* emb     = (const float*)d_in[2];
    const float* w_ih0   = (const float*)d_in[3];
    const float* w_hh0   = (const float*)d_in[4];
    const float* b_ih0   = (const float*)d_in[5];
    const float* b_hh0   = (const float*)d_in[6];
    const float* w_ih1   = (const float*)d_in[7];
    const float* w_hh1   = (const float*)d_in[8];
    const float* b_ih1   = (const float*)d_in[9];
    const float* b_hh1   = (const float*)d_in[10];
    const float* w_ih2   = (const float*)d_in[11];
    const float* w_hh2   = (const float*)d_in[12];
    const float* b_ih2   = (const float*)d_in[13];
    const float* b_hh2   = (const float*)d_in[14];
    const float* w_fc    = (const float*)d_in[15];
    const float* b_fc    = (const float*)d_in[16];
    float* out = (float*)d_out;

    float* xg = (float*)d_ws;                  // [BT, 400]  ~210 MB
    float* hs = xg + (size_t)BT * GATES;       // [BT, 100]  ~52 MB

    const int nblk = (BT / 128) * 4;   // 4096, XCD-swizzled inside kernel

    // Layer 0: embedding gather fused into staging, K=300 (pad 320)
    xg_gemm<300, 10, true><<<nblk, 256, 0, stream>>>(emb, x, w_ih0, b_ih0, b_hh0, lengths, xg);
    lstm_recur<true><<<BATCH, 448, 0, stream>>>(xg, w_hh0, lengths, hs);

    // Layer 1: K=100 (pad 128)
    xg_gemm<100, 4, false><<<nblk, 256, 0, stream>>>(hs, nullptr, w_ih1, b_ih1, b_hh1, lengths, xg);
    lstm_recur<true><<<BATCH, 448, 0, stream>>>(xg, w_hh1, lengths, hs);

    // Layer 2
    xg_gemm<100, 4, false><<<nblk, 256, 0, stream>>>(hs, nullptr, w_ih2, b_ih2, b_hh2, lengths, xg);
    lstm_recur<false><<<BATCH, 448, 0, stream>>>(xg, w_hh2, lengths, hs);

    // Head
    fc_kernel<<<(BATCH * 3 + 63) / 64, 64, 0, stream>>>(hs, w_fc, b_fc, out);
}